// Round 2
// baseline (51.692 us; speedup 1.0000x reference)
//
#include <hip/hip_runtime.h>
#include <hip/hip_bf16.h>

// Problem: B=4, L=2048, E=512, D=128
//   dep[b,l,d]   = sum_e emb[b,l,e] * W[d,e]
//   dist[b,i,j]  = sq[i] + sq[j] - 2 * dep_b . dep_b
// d_out = dep (4*2048*128 f32) ++ distances (4*2048*2048 f32)
//
// Round 2: all-register MFMA kernels, zero LDS, zero barriers.
//  - kW: W f32 -> bf16 once (65K elems)
//  - kA: grid 256 blocks, per-wave 32x32 output, frags loaded direct from
//        global (emb f32 converted in-register; W_bf16 L2-hot)
//  - kB: grid 1024 blocks, per-wave 64x64, frags direct from L2-resident
//        dep_b16; write-bound epilogue

typedef __attribute__((ext_vector_type(8))) short  short8;   // 8 bf16
typedef __attribute__((ext_vector_type(4))) float  floatx4;  // MFMA C/D frag

#define B_  4
#define L_  2048
#define E_  512
#define D_  128
#define M_  (B_*L_)   // 8192

__device__ __forceinline__ unsigned short f2bf(float x) {
    union { float f; unsigned u; } v; v.f = x;
    unsigned r = v.u + 0x7FFF + ((v.u >> 16) & 1);   // round-to-nearest-even
    return (unsigned short)(r >> 16);
}

// ---------------- kW: W f32 -> bf16 ----------------------------------------
__global__ __launch_bounds__(256)
void kW(const float* __restrict__ W, unsigned short* __restrict__ Wb)
{
    int i = (blockIdx.x * 256 + threadIdx.x) * 4;     // 64 blocks cover 65536
    float4 v = *reinterpret_cast<const float4*>(W + i);
    ushort4 u;
    u.x = f2bf(v.x); u.y = f2bf(v.y); u.z = f2bf(v.z); u.w = f2bf(v.w);
    *reinterpret_cast<ushort4*>(Wb + i) = u;
}

// ---------------- kA: dep = emb @ W^T  (M=8192, N=128, K=512) ---------------
// 256 blocks x 256 thr. Block tile 32 rows x 128 cols; 4 waves N-split,
// per-wave 32x32. No LDS, no barriers.
__global__ __launch_bounds__(256)
void kA(const float* __restrict__ emb, const unsigned short* __restrict__ Wb,
        float* __restrict__ dep_out, unsigned short* __restrict__ dep_b16)
{
    const int lane = threadIdx.x & 63;
    const int wave = threadIdx.x >> 6;          // cols wave*32 .. +31
    const int l15 = lane & 15, lg = lane >> 4;
    const long m0 = (long)blockIdx.x * 32;

    floatx4 acc[2][2];
    #pragma unroll
    for (int i = 0; i < 2; ++i)
        #pragma unroll
        for (int j = 0; j < 2; ++j)
            acc[i][j] = (floatx4){0.f, 0.f, 0.f, 0.f};

    const float* a0 = emb + (m0 + l15) * E_;
    const float* a1 = emb + (m0 + 16 + l15) * E_;
    const unsigned short* b0 = Wb + (wave * 32 + l15) * E_;
    const unsigned short* b1 = Wb + (wave * 32 + 16 + l15) * E_;

    #pragma unroll
    for (int k0 = 0; k0 < E_; k0 += 32) {
        const int kc = k0 + lg * 8;
        short8 af[2], bf[2];
        #pragma unroll
        for (int mi = 0; mi < 2; ++mi) {
            const float* ap = (mi == 0 ? a0 : a1) + kc;
            float4 x = *reinterpret_cast<const float4*>(ap);
            float4 y = *reinterpret_cast<const float4*>(ap + 4);
            short8 t;
            t[0] = (short)f2bf(x.x); t[1] = (short)f2bf(x.y);
            t[2] = (short)f2bf(x.z); t[3] = (short)f2bf(x.w);
            t[4] = (short)f2bf(y.x); t[5] = (short)f2bf(y.y);
            t[6] = (short)f2bf(y.z); t[7] = (short)f2bf(y.w);
            af[mi] = t;
        }
        bf[0] = *reinterpret_cast<const short8*>(b0 + kc);
        bf[1] = *reinterpret_cast<const short8*>(b1 + kc);
        #pragma unroll
        for (int mi = 0; mi < 2; ++mi)
            #pragma unroll
            for (int ni = 0; ni < 2; ++ni)
                acc[mi][ni] = __builtin_amdgcn_mfma_f32_16x16x32_bf16(
                    af[mi], bf[ni], acc[mi][ni], 0, 0, 0);
    }

    // C/D layout: col = lane&15, row = (lane>>4)*4 + j  [m89-verified]
    #pragma unroll
    for (int mi = 0; mi < 2; ++mi) {
        #pragma unroll
        for (int j = 0; j < 4; ++j) {
            long row = m0 + mi * 16 + lg * 4 + j;
            #pragma unroll
            for (int ni = 0; ni < 2; ++ni) {
                int col = wave * 32 + ni * 16 + l15;
                float v = acc[mi][ni][j];
                dep_out[row * D_ + col] = v;
                dep_b16[row * D_ + col] = f2bf(v);
            }
        }
    }
}

// ---------------- kSQ: sq[row] = sum_d dep_b16[row][d]^2 --------------------
__global__ __launch_bounds__(256)
void kSQ(const unsigned short* __restrict__ dep_b16, float* __restrict__ sq)
{
    int row  = blockIdx.x * 4 + (threadIdx.x >> 6);
    int lane = threadIdx.x & 63;
    unsigned v = *reinterpret_cast<const unsigned*>(dep_b16 + (long)row * D_ + lane * 2);
    union { unsigned u; float f; } a, b;
    a.u = v << 16; b.u = v & 0xFFFF0000u;
    float s = a.f * a.f + b.f * b.f;
    #pragma unroll
    for (int off = 32; off; off >>= 1) s += __shfl_down(s, off);
    if (lane == 0) sq[row] = s;
}

// ---------------- kB: dist = sq_i + sq_j - 2 * dep dep^T --------------------
// 1024 blocks x 256 thr, 4 waves 2x2, per-wave 64x64. Frags loaded direct
// from L2-resident dep_b16 (512KB/batch). No LDS, no barriers.
__global__ __launch_bounds__(256)
void kB(const unsigned short* __restrict__ dep_b16, const float* __restrict__ sq,
        float* __restrict__ dist)
{
    const int tid  = threadIdx.x;
    const int lane = tid & 63;
    const int wave = tid >> 6;
    const int wr = wave >> 1, wc = wave & 1;
    const int l15 = lane & 15, lg = lane >> 4;
    const int b  = blockIdx.z;
    const int i0 = blockIdx.y * 128;
    const int j0 = blockIdx.x * 128;
    const unsigned short* depb = dep_b16 + (long)b * L_ * D_;

    floatx4 acc[4][4];
    #pragma unroll
    for (int i = 0; i < 4; ++i)
        #pragma unroll
        for (int j = 0; j < 4; ++j)
            acc[i][j] = (floatx4){0.f, 0.f, 0.f, 0.f};

    const unsigned short* ibase = depb + (long)(i0 + wr * 64 + l15) * D_;
    const unsigned short* jbase = depb + (long)(j0 + wc * 64 + l15) * D_;

    #pragma unroll
    for (int kk = 0; kk < 4; ++kk) {
        const int kc = kk * 32 + lg * 8;
        short8 af[4], bf[4];
        #pragma unroll
        for (int mi = 0; mi < 4; ++mi)
            af[mi] = *reinterpret_cast<const short8*>(ibase + (long)mi * 16 * D_ + kc);
        #pragma unroll
        for (int ni = 0; ni < 4; ++ni)
            bf[ni] = *reinterpret_cast<const short8*>(jbase + (long)ni * 16 * D_ + kc);
        #pragma unroll
        for (int mi = 0; mi < 4; ++mi)
            #pragma unroll
            for (int ni = 0; ni < 4; ++ni)
                acc[mi][ni] = __builtin_amdgcn_mfma_f32_16x16x32_bf16(
                    af[mi], bf[ni], acc[mi][ni], 0, 0, 0);
    }

    const float* sqb = sq + b * L_;
    float sqc[4];
    #pragma unroll
    for (int ni = 0; ni < 4; ++ni)
        sqc[ni] = sqb[j0 + wc * 64 + ni * 16 + l15];

    float* db = dist + (long)b * L_ * L_;
    #pragma unroll
    for (int mi = 0; mi < 4; ++mi) {
        #pragma unroll
        for (int j = 0; j < 4; ++j) {
            int row = i0 + wr * 64 + mi * 16 + lg * 4 + j;
            float sr = sqb[row];
            #pragma unroll
            for (int ni = 0; ni < 4; ++ni) {
                int col = j0 + wc * 64 + ni * 16 + l15;
                db[(long)row * L_ + col] = sr + sqc[ni] - 2.0f * acc[mi][ni][j];
            }
        }
    }
}

extern "C" void kernel_launch(void* const* d_in, const int* in_sizes, int n_in,
                              void* d_out, int out_size, void* d_ws, size_t ws_size,
                              hipStream_t stream)
{
    const float* emb = (const float*)d_in[0];   // [B,L,E] f32
    const float* W   = (const float*)d_in[1];   // [D,E]   f32

    float* dep_out = (float*)d_out;                       // [B*L, D]
    float* dist    = dep_out + (size_t)M_ * D_;           // [B, L, L]

    unsigned short* dep_b16 = (unsigned short*)d_ws;      // 2 MB
    float* sq  = (float*)((char*)d_ws + (size_t)M_ * D_ * sizeof(unsigned short)); // 32 KB
    unsigned short* Wb = (unsigned short*)((char*)d_ws
                         + (size_t)M_ * D_ * sizeof(unsigned short)
                         + (size_t)M_ * sizeof(float));   // 128 KB

    hipLaunchKernelGGL(kW,  dim3((D_ * E_) / (256 * 4)), dim3(256), 0, stream, W, Wb);
    hipLaunchKernelGGL(kA,  dim3(M_ / 32), dim3(256), 0, stream, emb, Wb, dep_out, dep_b16);
    hipLaunchKernelGGL(kSQ, dim3(M_ / 4),  dim3(256), 0, stream, dep_b16, sq);
    hipLaunchKernelGGL(kB,  dim3(L_ / 128, L_ / 128, B_), dim3(256), 0, stream,
                       dep_b16, sq, dist);
}